// Round 29
// baseline (120.155 us; speedup 1.0000x reference)
//
#include <hip/hip_runtime.h>
#include <hip/hip_bf16.h>

typedef __attribute__((ext_vector_type(8))) short short8v;   // bf16x8 fragment
typedef __attribute__((ext_vector_type(4))) float float4v;   // fp32x4 accum
typedef unsigned short ushort;
typedef unsigned int uint;

namespace {

constexpr int Hh = 192, Ww = 192, Cc = 16, Oo = 64, Bb = 4;
constexpr int TH = 4, TW = 32, NT = 128;     // 4x32 pixel tile, 128 threads (2 waves)
constexpr int HW = Hh * Ww;                  // 36864
constexpr int NPL = Bb * Cc;                 // 64 planes
constexpr int PVG_PLANE = 236 * 198;         // col-prefix plane
constexpr int PHG_PLANE = 198 * 236;         // row-prefix plane
// prep decomposition (256-thread blocks):
constexpr int PH_ROWS = NPL * 198;           // 12672 rows, 1 wave each
constexpr int PH_B    = PH_ROWS / 4;         // 3168 blocks (4 waves/block)
constexpr int PV_B    = (NPL * 198 + 255) / 256;   // 50
constexpr int WP_B    = 65536 / 256;         // 256
constexpr int PREP_B  = PH_B + PV_B + WP_B;  // 3474

// reflect-pad(3) + clip index map; valid for u in [-21, 213]
__device__ __forceinline__ int mapIdx(int u) {
    if (u < 0) { u = -u; if (u > 3) u = 3; }
    else if (u > 191) { u = 382 - u; if (u < 188) u = 188; }
    return u;
}

// RNE fp32->bf16 bits (native; pairs fuse to v_cvt_pk_bf16_f32)
__device__ __forceinline__ ushort f2bf(float f) {
    __hip_bfloat16 h = __float2bfloat16(f);
    return __builtin_bit_cast(ushort, h);
}

// Merged prep (256-thread blocks): PH wave-scans / PV serial / weight conversion.
__global__ __launch_bounds__(256)
void prep(const float* __restrict__ x, const float* __restrict__ wgt,
          float* __restrict__ pvg, float* __restrict__ phg, ushort* __restrict__ wbf)
{
    const int bid = blockIdx.x, tid = threadIdx.x;
    if (bid < PH_B) {
        const int lane = tid & 63;
        const int row  = bid * 4 + (tid >> 6);
        const int plane = row / 198;
        const int q     = row - plane * 198;
        const float* xp = x + (size_t)plane * HW;
        const int rsrc  = mapIdx(q - 3) * Ww;
        float* ph = phg + (size_t)plane * PHG_PLANE + (size_t)q * 236;
        if (lane == 0) ph[0] = 0.f;
        float carry = 0.f;
#pragma unroll
        for (int ck = 0; ck < 4; ++ck) {
            const int idx = ck * 64 + lane;
            float v = (idx < 235) ? xp[rsrc + mapIdx(idx - 21)] : 0.f;
#pragma unroll
            for (int d = 1; d < 64; d <<= 1) {
                float t2 = __shfl_up(v, d);
                if (lane >= d) v += t2;
            }
            if (idx < 235) ph[idx + 1] = v + carry;
            carry += __shfl(v, 63);
        }
        return;
    }
    if (bid < PH_B + PV_B) {
        const int t = (bid - PH_B) * 256 + tid;
        if (t >= NPL * 198) return;
        const int plane = t / 198;
        const int q     = t - plane * 198;
        const float* xp = x + (size_t)plane * HW;
        const int wsrc = mapIdx(q - 3);
        float* pv = pvg + (size_t)plane * PVG_PLANE + q;
        float r = 0.f;
        pv[0] = 0.f;
        for (int t0 = 0; t0 < 235; t0 += 5) {
            float v0 = xp[mapIdx(t0 - 21) * Ww + wsrc];
            float v1 = xp[mapIdx(t0 - 20) * Ww + wsrc];
            float v2 = xp[mapIdx(t0 - 19) * Ww + wsrc];
            float v3 = xp[mapIdx(t0 - 18) * Ww + wsrc];
            float v4 = xp[mapIdx(t0 - 17) * Ww + wsrc];
            float* pd = pv + (size_t)(t0 + 1) * 198;
            r += v0; pd[0]   = r;
            r += v1; pd[198] = r;
            r += v2; pd[396] = r;
            r += v3; pd[594] = r;
            r += v4; pd[792] = r;
        }
        return;
    }
    {
        const int t = (bid - PH_B - PV_B) * 256 + tid;   // 65536 entries
        const int k = t & 63, o = (t >> 6) & 63, c = t >> 12;
        wbf[t] = (k < 49) ? f2bf(wgt[o * 784 + c * 49 + k]) : (ushort)0;
    }
}

// Direct 16-channel kernel; deduped features; featB k-stride 56 (zero B-frag for k>=56).
__global__ __launch_bounds__(NT, 3)
void fova29(const ushort* __restrict__ wbf, const float* __restrict__ bias,
            const float* __restrict__ pvg, const float* __restrict__ phg,
            float* __restrict__ out)
{
    __shared__ __align__(16) ushort featB[NT][56];   // 14336 B, 112B rows (16B-aligned)
    __shared__ __align__(16) ushort wlds[64][72];    //  9216 B
    __shared__ float  pvt[27][40];                   //  4320 B
    __shared__ float  pht[10][76];                   //  3040 B  (total 30912 -> 5 blk/CU)

    const int tid  = threadIdx.x;
    const int lane = tid & 63;
    const int wv   = tid >> 6;          // wave id 0/1
    const int w0   = blockIdx.x * TW;
    const int h0   = blockIdx.y * TH;
    const int b    = blockIdx.z;
    const int ph_  = tid >> 5;          // pixel row 0..3 (tid == pixel id)
    const int pw   = tid & 31;

    float4v acc[4][4];
#pragma unroll
    for (int i = 0; i < 4; ++i)
#pragma unroll
        for (int j = 0; j < 4; ++j) acc[i][j] = (float4v)(0.f);

    // pad slots k=49..55 zeroed once (k=56..63 handled by zero B-frag register)
#pragma unroll
    for (int f = 49; f < 56; ++f) featB[tid][f] = 0;

    const float* pvsrc = pvg + (size_t)(b * Cc) * PVG_PLANE + (size_t)(h0 + 10) * 198 + w0;
    const float* phsrc = phg + (size_t)(b * Cc) * PHG_PLANE + (size_t)h0 * 236 + w0;
    const ushort* wsrc0 = wbf + tid * 32;

    // ---- prologue: stage tiles(c0) ----
    for (int idx = tid; idx < 27 * 38; idx += NT) {
        int r = idx / 38, c = idx - r * 38;
        pvt[r][c] = pvsrc[r * 198 + c];
    }
    for (int idx = tid; idx < 10 * 75; idx += NT) {
        int r = idx / 75, c = idx - r * 75;
        pht[r][c] = phsrc[r * 236 + c];
    }
    __syncthreads();

    for (int cc = 0; cc < Cc; ++cc) {
        // ---- W(c) regs: issue early ----
        short8v wreg[4];
#pragma unroll
        for (int q = 0; q < 4; ++q)
            wreg[q] = *(const short8v*)(&wsrc0[q * 8]);

        // ---- features (deduped; expressions bit-identical to fova27) ----
        {
            auto pk = [](float a, float bq) -> uint {
                return (uint)f2bf(a) | ((uint)f2bf(bq) << 16);
            };
            const float n9 = 1.f / 9.f, n15 = 1.f / 15.f, n39 = 1.f / 39.f;
            const int CB = pw + 21;
            uint4* fb = reinterpret_cast<uint4*>(&featB[tid][0]);
            uint4 U;

            // --- inner 3x3: 12 loads -> 9 diffs ---
            float i00, i10, i20, i01, i11, i21, i02, i12, i22;
            {
                float m2, m1, z0, p1;
                m2 = pvt[ph_ + 10][pw + 2]; m1 = pvt[ph_ + 11][pw + 2];
                z0 = pvt[ph_ + 12][pw + 2]; p1 = pvt[ph_ + 13][pw + 2];
                i00 = m1 - m2; i01 = z0 - m1; i02 = p1 - z0;
                m2 = pvt[ph_ + 10][pw + 3]; m1 = pvt[ph_ + 11][pw + 3];
                z0 = pvt[ph_ + 12][pw + 3]; p1 = pvt[ph_ + 13][pw + 3];
                i10 = m1 - m2; i11 = z0 - m1; i12 = p1 - z0;
                m2 = pvt[ph_ + 10][pw + 4]; m1 = pvt[ph_ + 11][pw + 4];
                z0 = pvt[ph_ + 12][pw + 4]; p1 = pvt[ph_ + 13][pw + 4];
                i20 = m1 - m2; i21 = z0 - m1; i22 = p1 - z0;
            }
            U.x = pk(i00, i10); U.y = pk(i20, i01);
            U.z = pk(i11, i21); U.w = pk(i02, i12);
            fb[0] = U;

            // --- ring5 shared V diffs (cols pw+1..pw+5) ---
            float r50 = pvt[ph_ + 14][pw + 1] - pvt[ph_ + 9][pw + 1];
            float r51 = pvt[ph_ + 14][pw + 2] - pvt[ph_ + 9][pw + 2];
            float r52 = pvt[ph_ + 14][pw + 3] - pvt[ph_ + 9][pw + 3];
            float r53 = pvt[ph_ + 14][pw + 4] - pvt[ph_ + 9][pw + 4];
            float r54 = pvt[ph_ + 14][pw + 5] - pvt[ph_ + 9][pw + 5];
            const float* hm2 = &pht[ph_ + 1][0];   // hdi=-2
            const float* hp2 = &pht[ph_ + 5][0];   // hdi=+2
            float f9  = (r50 + (hm2[CB + 3] - hm2[CB - 1])) * n9;
            float f13 = (r54 + (hm2[CB + 2] - hm2[CB - 2])) * n9;
            float s14 = (pht[ph_ + 2][CB + 3] - pht[ph_ + 2][CB - 2]) * 0.2f;
            U.x = pk(i22, f9); U.y = pk(r51 * 0.2f, r52 * 0.2f);
            U.z = pk(r53 * 0.2f, f13); U.w = pk(s14, s14);
            fb[1] = U;

            float s16 = (pht[ph_ + 3][CB + 3] - pht[ph_ + 3][CB - 2]) * 0.2f;
            float s18 = (pht[ph_ + 4][CB + 3] - pht[ph_ + 4][CB - 2]) * 0.2f;
            float f20 = (r50 + (hp2[CB + 3] - hp2[CB - 1])) * n9;
            U.x = pk(s16, s16); U.y = pk(s18, s18);
            U.z = pk(f20, r51 * 0.2f); U.w = pk(r52 * 0.2f, r53 * 0.2f);
            fb[2] = U;

            // --- ring7 down (rows -3): V = pvt[+23]-pvt[+8] ---
            const float* hm3 = &pht[ph_ + 0][0];
            const float* hp3 = &pht[ph_ + 6][0];
            float f24 = (r54 + (hp2[CB + 2] - hp2[CB - 2])) * n9;
            float d0 = pvt[ph_ + 23][pw + 0] - pvt[ph_ + 8][pw + 0];
            float d1 = pvt[ph_ + 23][pw + 1] - pvt[ph_ + 8][pw + 1];
            float d2 = pvt[ph_ + 23][pw + 2] - pvt[ph_ + 8][pw + 2];
            float d3 = pvt[ph_ + 23][pw + 3] - pvt[ph_ + 8][pw + 3];
            float d4 = pvt[ph_ + 23][pw + 4] - pvt[ph_ + 8][pw + 4];
            float d5 = pvt[ph_ + 23][pw + 5] - pvt[ph_ + 8][pw + 5];
            float d6 = pvt[ph_ + 23][pw + 6] - pvt[ph_ + 8][pw + 6];
            float f25 = (d0 + (hm3[CB + 22] - hm3[CB - 2])) * n39;
            float f31 = (d6 + (hm3[CB + 3] - hm3[CB - 21])) * n39;
            U.x = pk(f24, f25); U.y = pk(d1 * n15, d2 * n15);
            U.z = pk(d3 * n15, d4 * n15); U.w = pk(d5 * n15, f31);
            fb[3] = U;

            // --- H-only rows (0.04): rows ph_+1..ph_+4 ---
            {
                const float* r2 = &pht[ph_ + 2][0];
                const float* r3 = &pht[ph_ + 3][0];
                const float* r4 = &pht[ph_ + 4][0];
                float f32 = (hm2[CB + 22] - hm2[CB - 3]) * 0.04f;
                float f33 = (hm2[CB + 4]  - hm2[CB - 21]) * 0.04f;
                float f34 = (r2[CB + 22] - r2[CB - 3]) * 0.04f;
                float f35 = (r2[CB + 4]  - r2[CB - 21]) * 0.04f;
                float f36 = (r3[CB + 22] - r3[CB - 3]) * 0.04f;
                float f37 = (r3[CB + 4]  - r3[CB - 21]) * 0.04f;
                float f38 = (r4[CB + 22] - r4[CB - 3]) * 0.04f;
                float f39 = (r4[CB + 4]  - r4[CB - 21]) * 0.04f;
                U.x = pk(f32, f33); U.y = pk(f34, f35);
                U.z = pk(f36, f37); U.w = pk(f38, f39);
                fb[4] = U;
            }

            // --- ring7 up (rows +3): V = pvt[+15]-pvt[+0] ---
            {
                float f40 = (hp2[CB + 22] - hp2[CB - 3]) * 0.04f;
                float f41 = (hp2[CB + 4]  - hp2[CB - 21]) * 0.04f;
                float u0 = pvt[ph_ + 15][pw + 0] - pvt[ph_ + 0][pw + 0];
                float u1 = pvt[ph_ + 15][pw + 1] - pvt[ph_ + 0][pw + 1];
                float u2 = pvt[ph_ + 15][pw + 2] - pvt[ph_ + 0][pw + 2];
                float u3 = pvt[ph_ + 15][pw + 3] - pvt[ph_ + 0][pw + 3];
                float u4 = pvt[ph_ + 15][pw + 4] - pvt[ph_ + 0][pw + 4];
                float u5 = pvt[ph_ + 15][pw + 5] - pvt[ph_ + 0][pw + 5];
                float u6 = pvt[ph_ + 15][pw + 6] - pvt[ph_ + 0][pw + 6];
                float f42 = (u0 + (hp3[CB + 22] - hp3[CB - 2])) * n39;
                float f48 = (u6 + (hp3[CB + 3]  - hp3[CB - 21])) * n39;
                U.x = pk(f40, f41); U.y = pk(f42, u1 * n15);
                U.z = pk(u2 * n15, u3 * n15); U.w = pk(u4 * n15, u5 * n15);
                fb[5] = U;
                featB[tid][48] = f2bf(f48);
            }
        }
        // ---- wlds write (R27 mapping; VGPR-cheapest) ----
        {
            const int base = tid * 4;
#pragma unroll
            for (int q = 0; q < 4; ++q) {
                const int idx = base + q;
                *(short8v*)(&wlds[idx >> 3][(idx & 7) * 8]) = wreg[q];
            }
        }
        __syncthreads();   // featB/wlds ready; all tile reads done

        // ---- stage-loads(c+1): issue BEFORE MFMA ----
        float pvr[9], phr[6];
        const bool more = (cc + 1 < Cc);
        if (more) {
            const float* pvn = pvsrc + PVG_PLANE;
            const float* phn = phsrc + PHG_PLANE;
#pragma unroll
            for (int k = 0; k < 9; ++k) {
                int idx = tid + k * NT;
                if (idx < 27 * 38) pvr[k] = pvn[(idx / 38) * 198 + (idx % 38)];
            }
#pragma unroll
            for (int k = 0; k < 6; ++k) {
                int idx = tid + k * NT;
                if (idx < 10 * 75) phr[k] = phn[(idx / 75) * 236 + (idx % 75)];
            }
        }

        // ---- MFMA(c): A from wlds (b128), B from featB (b128, zero for k>=56) ----
        {
            const int olo = lane & 15, kg = lane >> 4;
            const short8v zero8 = __builtin_bit_cast(short8v, uint4{0u, 0u, 0u, 0u});
#pragma unroll
            for (int kc = 0; kc < 2; ++kc) {
                const int k0 = kc * 32 + kg * 8;
                short8v afr[4];
#pragma unroll
                for (int ob = 0; ob < 4; ++ob) {
                    const int o = ob * 16 + olo;
                    afr[ob] = *(const short8v*)(&wlds[o][k0]);
                }
                short8v bfr[4];
#pragma unroll
                for (int nb = 0; nb < 4; ++nb) {
                    const int p = wv * 64 + nb * 16 + olo;
                    bfr[nb] = (k0 < 56) ? *(const short8v*)(&featB[p][k0]) : zero8;
                }
#pragma unroll
                for (int ob = 0; ob < 4; ++ob)
#pragma unroll
                    for (int nb = 0; nb < 4; ++nb)
                        acc[ob][nb] = __builtin_amdgcn_mfma_f32_16x16x32_bf16(
                            afr[ob], bfr[nb], acc[ob][nb], 0, 0, 0);
            }
        }

        // ---- write tiles(c+1) ----
        if (more) {
#pragma unroll
            for (int k = 0; k < 9; ++k) {
                int idx = tid + k * NT;
                if (idx < 27 * 38) pvt[idx / 38][idx % 38] = pvr[k];
            }
#pragma unroll
            for (int k = 0; k < 6; ++k) {
                int idx = tid + k * NT;
                if (idx < 10 * 75) pht[idx / 75][idx % 75] = phr[k];
            }
        }
        __syncthreads();   // MFMA done; tiles(c+1) ready

        pvsrc += PVG_PLANE; phsrc += PHG_PLANE; wsrc0 += 4096;
    }

    // ---- epilogue: direct store with bias ----
#pragma unroll
    for (int ob = 0; ob < 4; ++ob)
#pragma unroll
        for (int nb = 0; nb < 4; ++nb) {
            const int p = wv * 64 + nb * 16 + (lane & 15);
            const int hh = h0 + (p >> 5), ww2 = w0 + (p & 31);
            const int o0 = ob * 16 + ((lane >> 4) << 2);
            float4v a = acc[ob][nb];
#pragma unroll
            for (int r = 0; r < 4; ++r) {
                const int o = o0 + r;
                out[(((size_t)b * Oo + o) * Hh + hh) * Ww + ww2] = a[r] + bias[o];
            }
        }
}

} // namespace

extern "C" void kernel_launch(void* const* d_in, const int* in_sizes, int n_in,
                              void* d_out, int out_size, void* d_ws, size_t ws_size,
                              hipStream_t stream) {
    (void)in_sizes; (void)n_in; (void)out_size; (void)ws_size;
    const float* x    = (const float*)d_in[0];
    const float* wgt  = (const float*)d_in[1];
    const float* bias = (const float*)d_in[2];
    float* out        = (float*)d_out;

    float* pvg  = (float*)d_ws;
    float* phg  = pvg + (size_t)NPL * PVG_PLANE;
    ushort* wbf = (ushort*)(phg + (size_t)NPL * PHG_PLANE);   // needs ~24.3 MB total

    prep<<<dim3(PREP_B), dim3(256), 0, stream>>>(x, wgt, pvg, phg, wbf);

    dim3 grid(Ww / TW, Hh / TH, Bb);   // 6 x 48 x 4 = 1152 blocks
    fova29<<<grid, dim3(NT), 0, stream>>>(wbf, bias, pvg, phg, out);
}

// Round 30
// 93.883 us; speedup vs baseline: 1.2798x; 1.2798x over previous
//
#include <hip/hip_runtime.h>
#include <hip/hip_bf16.h>

typedef __attribute__((ext_vector_type(8))) short short8v;   // bf16x8 fragment
typedef __attribute__((ext_vector_type(4))) float float4v;   // fp32x4 accum
typedef unsigned short ushort;
typedef unsigned int uint;

namespace {

constexpr int Hh = 192, Ww = 192, Cc = 16, Oo = 64, Bb = 4;
constexpr int TH = 4, TW = 32, NT = 128;     // 4x32 pixel tile, 128 threads (2 waves)
constexpr int HW = Hh * Ww;                  // 36864
constexpr int NPL = Bb * Cc;                 // 64 planes
constexpr int PVG_PLANE = 236 * 198;         // col-prefix plane
constexpr int PHG_PLANE = 198 * 236;         // row-prefix plane
// prep decomposition (256-thread blocks):
constexpr int PH_ROWS = NPL * 198;           // 12672 rows, 1 wave each
constexpr int PH_B    = PH_ROWS / 4;         // 3168 blocks (4 waves/block)
constexpr int PV_B    = (NPL * 198 + 255) / 256;   // 50
constexpr int WP_B    = 65536 / 256;         // 256
constexpr int PREP_B  = PH_B + PV_B + WP_B;  // 3474

// reflect-pad(3) + clip index map; valid for u in [-21, 213]
__device__ __forceinline__ int mapIdx(int u) {
    if (u < 0) { u = -u; if (u > 3) u = 3; }
    else if (u > 191) { u = 382 - u; if (u < 188) u = 188; }
    return u;
}

// RNE fp32->bf16 bits (native; pairs fuse to v_cvt_pk_bf16_f32)
__device__ __forceinline__ ushort f2bf(float f) {
    __hip_bfloat16 h = __float2bfloat16(f);
    return __builtin_bit_cast(ushort, h);
}

// Merged prep (256-thread blocks): PH wave-scans / PV serial / weight conversion.
__global__ __launch_bounds__(256)
void prep(const float* __restrict__ x, const float* __restrict__ wgt,
          float* __restrict__ pvg, float* __restrict__ phg, ushort* __restrict__ wbf)
{
    const int bid = blockIdx.x, tid = threadIdx.x;
    if (bid < PH_B) {
        const int lane = tid & 63;
        const int row  = bid * 4 + (tid >> 6);
        const int plane = row / 198;
        const int q     = row - plane * 198;
        const float* xp = x + (size_t)plane * HW;
        const int rsrc  = mapIdx(q - 3) * Ww;
        float* ph = phg + (size_t)plane * PHG_PLANE + (size_t)q * 236;
        if (lane == 0) ph[0] = 0.f;
        float carry = 0.f;
#pragma unroll
        for (int ck = 0; ck < 4; ++ck) {
            const int idx = ck * 64 + lane;
            float v = (idx < 235) ? xp[rsrc + mapIdx(idx - 21)] : 0.f;
#pragma unroll
            for (int d = 1; d < 64; d <<= 1) {
                float t2 = __shfl_up(v, d);
                if (lane >= d) v += t2;
            }
            if (idx < 235) ph[idx + 1] = v + carry;
            carry += __shfl(v, 63);
        }
        return;
    }
    if (bid < PH_B + PV_B) {
        const int t = (bid - PH_B) * 256 + tid;
        if (t >= NPL * 198) return;
        const int plane = t / 198;
        const int q     = t - plane * 198;
        const float* xp = x + (size_t)plane * HW;
        const int wsrc = mapIdx(q - 3);
        float* pv = pvg + (size_t)plane * PVG_PLANE + q;
        float r = 0.f;
        pv[0] = 0.f;
        for (int t0 = 0; t0 < 235; t0 += 5) {
            float v0 = xp[mapIdx(t0 - 21) * Ww + wsrc];
            float v1 = xp[mapIdx(t0 - 20) * Ww + wsrc];
            float v2 = xp[mapIdx(t0 - 19) * Ww + wsrc];
            float v3 = xp[mapIdx(t0 - 18) * Ww + wsrc];
            float v4 = xp[mapIdx(t0 - 17) * Ww + wsrc];
            float* pd = pv + (size_t)(t0 + 1) * 198;
            r += v0; pd[0]   = r;
            r += v1; pd[198] = r;
            r += v2; pd[396] = r;
            r += v3; pd[594] = r;
            r += v4; pd[792] = r;
        }
        return;
    }
    {
        const int t = (bid - PH_B - PV_B) * 256 + tid;   // 65536 entries
        const int k = t & 63, o = (t >> 6) & 63, c = t >> 12;
        wbf[t] = (k < 49) ? f2bf(wgt[o * 784 + c * 49 + k]) : (ushort)0;
    }
}

// Direct 16-channel kernel; feature phase deduped (bit-identical expressions).
__global__ __launch_bounds__(NT, 3)
void fova30(const ushort* __restrict__ wbf, const float* __restrict__ bias,
            const float* __restrict__ pvg, const float* __restrict__ phg,
            float* __restrict__ out)
{
    __shared__ __align__(16) ushort featB[NT][72];   // 18432 B, 144B rows (16B-aligned)
    __shared__ __align__(16) ushort wlds[64][72];    //  9216 B
    __shared__ float  pvt[27][40];                   //  4320 B
    __shared__ float  pht[10][76];                   //  3040 B  (total 35008 -> 4 blk/CU)

    const int tid  = threadIdx.x;
    const int lane = tid & 63;
    const int wv   = tid >> 6;          // wave id 0/1
    const int w0   = blockIdx.x * TW;
    const int h0   = blockIdx.y * TH;
    const int b    = blockIdx.z;
    const int ph_  = tid >> 5;          // pixel row 0..3 (tid == pixel id)
    const int pw   = tid & 31;

    float4v acc[4][4];
#pragma unroll
    for (int i = 0; i < 4; ++i)
#pragma unroll
        for (int j = 0; j < 4; ++j) acc[i][j] = (float4v)(0.f);

#pragma unroll
    for (int f = 49; f < 64; ++f) featB[tid][f] = 0;

    const float* pvsrc = pvg + (size_t)(b * Cc) * PVG_PLANE + (size_t)(h0 + 10) * 198 + w0;
    const float* phsrc = phg + (size_t)(b * Cc) * PHG_PLANE + (size_t)h0 * 236 + w0;
    const ushort* wsrc0 = wbf + tid * 32;

    // ---- prologue: stage tiles(c0) ----
    for (int idx = tid; idx < 27 * 38; idx += NT) {
        int r = idx / 38, c = idx - r * 38;
        pvt[r][c] = pvsrc[r * 198 + c];
    }
    for (int idx = tid; idx < 10 * 75; idx += NT) {
        int r = idx / 75, c = idx - r * 75;
        pht[r][c] = phsrc[r * 236 + c];
    }
    __syncthreads();

    for (int cc = 0; cc < Cc; ++cc) {
        // ---- W(c) regs: issue early ----
        short8v wreg[4];
#pragma unroll
        for (int q = 0; q < 4; ++q)
            wreg[q] = *(const short8v*)(&wsrc0[q * 8]);

        // ---- features (deduped; expressions bit-identical to fova26's FV) ----
        {
            auto pk = [](float a, float bq) -> uint {
                return (uint)f2bf(a) | ((uint)f2bf(bq) << 16);
            };
            const float n9 = 1.f / 9.f, n15 = 1.f / 15.f, n39 = 1.f / 39.f;
            const int CB = pw + 21;
            uint4* fb = reinterpret_cast<uint4*>(&featB[tid][0]);
            uint4 U;

            // --- inner 3x3: 12 loads -> 9 diffs ---
            float i00, i10, i20, i01, i11, i21, i02, i12, i22;
            {
                float m2, m1, z0, p1;
                m2 = pvt[ph_ + 10][pw + 2]; m1 = pvt[ph_ + 11][pw + 2];
                z0 = pvt[ph_ + 12][pw + 2]; p1 = pvt[ph_ + 13][pw + 2];
                i00 = m1 - m2; i01 = z0 - m1; i02 = p1 - z0;
                m2 = pvt[ph_ + 10][pw + 3]; m1 = pvt[ph_ + 11][pw + 3];
                z0 = pvt[ph_ + 12][pw + 3]; p1 = pvt[ph_ + 13][pw + 3];
                i10 = m1 - m2; i11 = z0 - m1; i12 = p1 - z0;
                m2 = pvt[ph_ + 10][pw + 4]; m1 = pvt[ph_ + 11][pw + 4];
                z0 = pvt[ph_ + 12][pw + 4]; p1 = pvt[ph_ + 13][pw + 4];
                i20 = m1 - m2; i21 = z0 - m1; i22 = p1 - z0;
            }
            U.x = pk(i00, i10); U.y = pk(i20, i01);
            U.z = pk(i11, i21); U.w = pk(i02, i12);
            fb[0] = U;

            // --- ring5 shared V diffs (cols pw+1..pw+5) ---
            float r50 = pvt[ph_ + 14][pw + 1] - pvt[ph_ + 9][pw + 1];
            float r51 = pvt[ph_ + 14][pw + 2] - pvt[ph_ + 9][pw + 2];
            float r52 = pvt[ph_ + 14][pw + 3] - pvt[ph_ + 9][pw + 3];
            float r53 = pvt[ph_ + 14][pw + 4] - pvt[ph_ + 9][pw + 4];
            float r54 = pvt[ph_ + 14][pw + 5] - pvt[ph_ + 9][pw + 5];
            const float* hm2 = &pht[ph_ + 1][0];   // hdi=-2
            const float* hp2 = &pht[ph_ + 5][0];   // hdi=+2
            float f9  = (r50 + (hm2[CB + 3] - hm2[CB - 1])) * n9;
            float f13 = (r54 + (hm2[CB + 2] - hm2[CB - 2])) * n9;
            float s14 = (pht[ph_ + 2][CB + 3] - pht[ph_ + 2][CB - 2]) * 0.2f;
            U.x = pk(i22, f9); U.y = pk(r51 * 0.2f, r52 * 0.2f);
            U.z = pk(r53 * 0.2f, f13); U.w = pk(s14, s14);
            fb[1] = U;

            float s16 = (pht[ph_ + 3][CB + 3] - pht[ph_ + 3][CB - 2]) * 0.2f;
            float s18 = (pht[ph_ + 4][CB + 3] - pht[ph_ + 4][CB - 2]) * 0.2f;
            float f20 = (r50 + (hp2[CB + 3] - hp2[CB - 1])) * n9;
            U.x = pk(s16, s16); U.y = pk(s18, s18);
            U.z = pk(f20, r51 * 0.2f); U.w = pk(r52 * 0.2f, r53 * 0.2f);
            fb[2] = U;

            // --- ring7 down (rows -3): V = pvt[+23]-pvt[+8] ---
            const float* hm3 = &pht[ph_ + 0][0];
            const float* hp3 = &pht[ph_ + 6][0];
            float f24 = (r54 + (hp2[CB + 2] - hp2[CB - 2])) * n9;
            float d0 = pvt[ph_ + 23][pw + 0] - pvt[ph_ + 8][pw + 0];
            float d1 = pvt[ph_ + 23][pw + 1] - pvt[ph_ + 8][pw + 1];
            float d2 = pvt[ph_ + 23][pw + 2] - pvt[ph_ + 8][pw + 2];
            float d3 = pvt[ph_ + 23][pw + 3] - pvt[ph_ + 8][pw + 3];
            float d4 = pvt[ph_ + 23][pw + 4] - pvt[ph_ + 8][pw + 4];
            float d5 = pvt[ph_ + 23][pw + 5] - pvt[ph_ + 8][pw + 5];
            float d6 = pvt[ph_ + 23][pw + 6] - pvt[ph_ + 8][pw + 6];
            float f25 = (d0 + (hm3[CB + 22] - hm3[CB - 2])) * n39;
            float f31 = (d6 + (hm3[CB + 3] - hm3[CB - 21])) * n39;
            U.x = pk(f24, f25); U.y = pk(d1 * n15, d2 * n15);
            U.z = pk(d3 * n15, d4 * n15); U.w = pk(d5 * n15, f31);
            fb[3] = U;

            // --- H-only rows (0.04): rows ph_+1..ph_+4 ---
            {
                const float* r2 = &pht[ph_ + 2][0];
                const float* r3 = &pht[ph_ + 3][0];
                const float* r4 = &pht[ph_ + 4][0];
                float f32 = (hm2[CB + 22] - hm2[CB - 3]) * 0.04f;
                float f33 = (hm2[CB + 4]  - hm2[CB - 21]) * 0.04f;
                float f34 = (r2[CB + 22] - r2[CB - 3]) * 0.04f;
                float f35 = (r2[CB + 4]  - r2[CB - 21]) * 0.04f;
                float f36 = (r3[CB + 22] - r3[CB - 3]) * 0.04f;
                float f37 = (r3[CB + 4]  - r3[CB - 21]) * 0.04f;
                float f38 = (r4[CB + 22] - r4[CB - 3]) * 0.04f;
                float f39 = (r4[CB + 4]  - r4[CB - 21]) * 0.04f;
                U.x = pk(f32, f33); U.y = pk(f34, f35);
                U.z = pk(f36, f37); U.w = pk(f38, f39);
                fb[4] = U;
            }

            // --- ring7 up (rows +3): V = pvt[+15]-pvt[+0] ---
            {
                float f40 = (hp2[CB + 22] - hp2[CB - 3]) * 0.04f;
                float f41 = (hp2[CB + 4]  - hp2[CB - 21]) * 0.04f;
                float u0 = pvt[ph_ + 15][pw + 0] - pvt[ph_ + 0][pw + 0];
                float u1 = pvt[ph_ + 15][pw + 1] - pvt[ph_ + 0][pw + 1];
                float u2 = pvt[ph_ + 15][pw + 2] - pvt[ph_ + 0][pw + 2];
                float u3 = pvt[ph_ + 15][pw + 3] - pvt[ph_ + 0][pw + 3];
                float u4 = pvt[ph_ + 15][pw + 4] - pvt[ph_ + 0][pw + 4];
                float u5 = pvt[ph_ + 15][pw + 5] - pvt[ph_ + 0][pw + 5];
                float u6 = pvt[ph_ + 15][pw + 6] - pvt[ph_ + 0][pw + 6];
                float f42 = (u0 + (hp3[CB + 22] - hp3[CB - 2])) * n39;
                float f48 = (u6 + (hp3[CB + 3]  - hp3[CB - 21])) * n39;
                U.x = pk(f40, f41); U.y = pk(f42, u1 * n15);
                U.z = pk(u2 * n15, u3 * n15); U.w = pk(u4 * n15, u5 * n15);
                fb[5] = U;
                featB[tid][48] = f2bf(f48);
            }
        }
        // ---- wlds write ----
        {
            const int base = tid * 4;
#pragma unroll
            for (int q = 0; q < 4; ++q) {
                const int idx = base + q;
                *(short8v*)(&wlds[idx >> 3][(idx & 7) * 8]) = wreg[q];
            }
        }
        __syncthreads();   // featB/wlds ready; all tile reads done

        // ---- stage-loads(c+1): issue BEFORE MFMA ----
        float pvr[9], phr[6];
        const bool more = (cc + 1 < Cc);
        if (more) {
            const float* pvn = pvsrc + PVG_PLANE;
            const float* phn = phsrc + PHG_PLANE;
#pragma unroll
            for (int k = 0; k < 9; ++k) {
                int idx = tid + k * NT;
                if (idx < 27 * 38) pvr[k] = pvn[(idx / 38) * 198 + (idx % 38)];
            }
#pragma unroll
            for (int k = 0; k < 6; ++k) {
                int idx = tid + k * NT;
                if (idx < 10 * 75) phr[k] = phn[(idx / 75) * 236 + (idx % 75)];
            }
        }

        // ---- MFMA(c): A from wlds (b128), B from featB (b128) ----
        {
            const int olo = lane & 15, kg = lane >> 4;
#pragma unroll
            for (int kc = 0; kc < 2; ++kc) {
                const int k0 = kc * 32 + kg * 8;
                short8v afr[4];
#pragma unroll
                for (int ob = 0; ob < 4; ++ob) {
                    const int o = ob * 16 + olo;
                    afr[ob] = *(const short8v*)(&wlds[o][k0]);
                }
                short8v bfr[4];
#pragma unroll
                for (int nb = 0; nb < 4; ++nb) {
                    const int p = wv * 64 + nb * 16 + olo;
                    bfr[nb] = *(const short8v*)(&featB[p][k0]);
                }
#pragma unroll
                for (int ob = 0; ob < 4; ++ob)
#pragma unroll
                    for (int nb = 0; nb < 4; ++nb)
                        acc[ob][nb] = __builtin_amdgcn_mfma_f32_16x16x32_bf16(
                            afr[ob], bfr[nb], acc[ob][nb], 0, 0, 0);
            }
        }

        // ---- write tiles(c+1) ----
        if (more) {
#pragma unroll
            for (int k = 0; k < 9; ++k) {
                int idx = tid + k * NT;
                if (idx < 27 * 38) pvt[idx / 38][idx % 38] = pvr[k];
            }
#pragma unroll
            for (int k = 0; k < 6; ++k) {
                int idx = tid + k * NT;
                if (idx < 10 * 75) pht[idx / 75][idx % 75] = phr[k];
            }
        }
        __syncthreads();   // MFMA done; tiles(c+1) ready

        pvsrc += PVG_PLANE; phsrc += PHG_PLANE; wsrc0 += 4096;
    }

    // ---- epilogue: direct store with bias ----
#pragma unroll
    for (int ob = 0; ob < 4; ++ob)
#pragma unroll
        for (int nb = 0; nb < 4; ++nb) {
            const int p = wv * 64 + nb * 16 + (lane & 15);
            const int hh = h0 + (p >> 5), ww2 = w0 + (p & 31);
            const int o0 = ob * 16 + ((lane >> 4) << 2);
            float4v a = acc[ob][nb];
#pragma unroll
            for (int r = 0; r < 4; ++r) {
                const int o = o0 + r;
                out[(((size_t)b * Oo + o) * Hh + hh) * Ww + ww2] = a[r] + bias[o];
            }
        }
}

} // namespace

extern "C" void kernel_launch(void* const* d_in, const int* in_sizes, int n_in,
                              void* d_out, int out_size, void* d_ws, size_t ws_size,
                              hipStream_t stream) {
    (void)in_sizes; (void)n_in; (void)out_size; (void)ws_size;
    const float* x    = (const float*)d_in[0];
    const float* wgt  = (const float*)d_in[1];
    const float* bias = (const float*)d_in[2];
    float* out        = (float*)d_out;

    float* pvg  = (float*)d_ws;
    float* phg  = pvg + (size_t)NPL * PVG_PLANE;
    ushort* wbf = (ushort*)(phg + (size_t)NPL * PHG_PLANE);   // needs ~24.3 MB total

    prep<<<dim3(PREP_B), dim3(256), 0, stream>>>(x, wgt, pvg, phg, wbf);

    dim3 grid(Ww / TW, Hh / TH, Bb);   // 6 x 48 x 4 = 1152 blocks
    fova30<<<grid, dim3(NT), 0, stream>>>(wbf, bias, pvg, phg, out);
}